// Round 7
// baseline (86.626 us; speedup 1.0000x reference)
//
#include <hip/hip_runtime.h>

#define BB 8
#define HH 512
#define WW 512
#define HW (HH * WW)

#define TW 32          // tile width
#define TH 32          // tile height
#define LR 38          // staged rows (TH+6)
#define LC 38          // staged cols (TW+6)
#define LS 40          // LDS row stride (dwords)
#define PLANE (LR * LS)

__device__ __forceinline__ int reflect512(int v) {
    v = v < 0 ? -v : v;
    return v >= 512 ? 1022 - v : v;
}

// Each thread computes a 2x2 output quad. Window rows are loaded from LDS
// once per thread and feed both output rows from registers (vertical reuse).
__global__ __launch_bounds__(256) void bilateral22(const float* __restrict__ in,
                                                   float* __restrict__ out) {
    __shared__ float lds[3 * PLANE];   // 18,240 B

    const int bx = blockIdx.x & 15;          // 512/32 = 16 tiles per dim
    const int by = (blockIdx.x >> 4) & 15;
    const int b  = blockIdx.x >> 8;
    const int x0 = bx * TW, y0 = by * TH;
    const int tx = threadIdx.x;              // 0..15 (2 cols each)
    const int ty = threadIdx.y;              // 0..15 (2 rows each)
    const int tid = ty * 16 + tx;

    const float* __restrict__ src = in + (size_t)b * 3 * HW;

    // ---- stage 38x38 tile+halo per channel (reflect once, here) ----
    for (int e = tid; e < 3 * LR * LC; e += 256) {
        int ch  = e / (LR * LC);
        int rem = e - ch * (LR * LC);
        int r   = rem / LC;
        int c   = rem - r * LC;
        lds[ch * PLANE + r * LS + c] =
            src[ch * HW + reflect512(y0 + r - 3) * WW + reflect512(x0 + c - 3)];
    }
    __syncthreads();

    const float* L0 = lds;
    const float* L1 = lds + PLANE;
    const float* L2 = lds + 2 * PLANE;
    const int col0 = 2 * tx;                 // window base col (staged space)

    // centers: staged rows 2ty+3+p, cols col0+3+w
    float c0[2][2], c1[2][2], c2[2][2];
    #pragma unroll
    for (int p = 0; p < 2; ++p) {
        int ci = (2 * ty + 3 + p) * LS + col0 + 3;
        c0[p][0] = L0[ci]; c0[p][1] = L0[ci + 1];
        c1[p][0] = L1[ci]; c1[p][1] = L1[ci + 1];
        c2[p][0] = L2[ci]; c2[p][1] = L2[ci + 1];
    }

    float n0[2][2] = {}, n1[2][2] = {}, n2[2][2] = {}, dn[2][2] = {};

    // log2 of unnormalized 1-D spatial gaussian (normalization cancels)
    const float ls7[7] = {-0.01472138f, -0.00654284f, -0.00163571f, 0.f,
                          -0.00163571f, -0.00654284f, -0.01472138f};
    const float K2 = -0.00721347520445f;     // (-0.5/10^2) * log2(e)

    #pragma unroll
    for (int i = 0; i < 8; ++i) {            // staged rows 2ty .. 2ty+7
        const int ro = (2 * ty + i) * LS + col0;
        float q0[8], q1[8], q2[8];
        {   float2 a = *(const float2*)(L0 + ro),     bq = *(const float2*)(L0 + ro + 2),
                   c = *(const float2*)(L0 + ro + 4), dq = *(const float2*)(L0 + ro + 6);
            q0[0]=a.x; q0[1]=a.y; q0[2]=bq.x; q0[3]=bq.y; q0[4]=c.x; q0[5]=c.y; q0[6]=dq.x; q0[7]=dq.y; }
        {   float2 a = *(const float2*)(L1 + ro),     bq = *(const float2*)(L1 + ro + 2),
                   c = *(const float2*)(L1 + ro + 4), dq = *(const float2*)(L1 + ro + 6);
            q1[0]=a.x; q1[1]=a.y; q1[2]=bq.x; q1[3]=bq.y; q1[4]=c.x; q1[5]=c.y; q1[6]=dq.x; q1[7]=dq.y; }
        {   float2 a = *(const float2*)(L2 + ro),     bq = *(const float2*)(L2 + ro + 2),
                   c = *(const float2*)(L2 + ro + 4), dq = *(const float2*)(L2 + ro + 6);
            q2[0]=a.x; q2[1]=a.y; q2[2]=bq.x; q2[3]=bq.y; q2[4]=c.x; q2[5]=c.y; q2[6]=dq.x; q2[7]=dq.y; }

        #pragma unroll
        for (int p = 0; p < 2; ++p) {        // output row p: staged window rows
            const int dy = i - p;            //   2ty+p+dy  ->  dy = i - p
            if (dy < 0 || dy > 6) continue;  // statically eliminated
            #pragma unroll
            for (int dx = 0; dx < 7; ++dx) {
                const float lw = ls7[dy] + ls7[dx];   // compile-time literal
                #pragma unroll
                for (int w = 0; w < 2; ++w) {
                    const int jc = dx + w;
                    float a0 = q0[jc], a1 = q1[jc], a2 = q2[jc];
                    float d = fabsf(a0 - c0[p][w]) + fabsf(a1 - c1[p][w]) + fabsf(a2 - c2[p][w]);
                    float wt = __builtin_amdgcn_exp2f(fmaf(K2, d * d, lw));
                    n0[p][w] += wt * a0;
                    n1[p][w] += wt * a1;
                    n2[p][w] += wt * a2;
                    dn[p][w] += wt;
                }
            }
        }
    }

    #pragma unroll
    for (int p = 0; p < 2; ++p) {
        float i0 = 1.0f / dn[p][0], i1 = 1.0f / dn[p][1];
        size_t ob = (size_t)b * 3 * HW + (size_t)(y0 + 2 * ty + p) * WW + x0 + col0;
        *(float2*)(out + ob)          = make_float2(n0[p][0] * i0, n0[p][1] * i1);
        *(float2*)(out + ob + HW)     = make_float2(n1[p][0] * i0, n1[p][1] * i1);
        *(float2*)(out + ob + 2*HW)   = make_float2(n2[p][0] * i0, n2[p][1] * i1);
    }
}

extern "C" void kernel_launch(void* const* d_in, const int* in_sizes, int n_in,
                              void* d_out, int out_size, void* d_ws, size_t ws_size,
                              hipStream_t stream) {
    const float* in = (const float*)d_in[0];
    float* out = (float*)d_out;
    dim3 block(16, 16, 1);
    int blocks = (WW / TW) * (HH / TH) * BB;   // 16*16*8 = 2048
    bilateral22<<<blocks, block, 0, stream>>>(in, out);
}

// Round 8
// 46.934 us; speedup vs baseline: 1.8457x; 1.8457x over previous
//
#include <hip/hip_runtime.h>

#define BB 8
#define HH 512
#define WW 512
#define HW (HH * WW)
#define STRIP 16   // rows marched per thread

__device__ __forceinline__ int reflect512(int v) {
    v = v < 0 ? -v : v;
    return v >= 512 ? 1022 - v : v;
}

// One thread per output column segment: window (7x7x3) lives in registers,
// rotated with a mod-7 slot scheme (all indices compile-time -> no scratch).
// Per step only the incoming row (7 cols x 3 ch) is loaded from global.
__global__ __launch_bounds__(256, 2) void bilateral_march(const float* __restrict__ in,
                                                          float* __restrict__ out) {
    const int blk   = blockIdx.x;
    const int b     = blk >> 6;          // 64 blocks per image
    const int rem   = blk & 63;
    const int strip = rem >> 1;          // 0..31
    const int xh    = rem & 1;
    const int x     = xh * 256 + threadIdx.x;
    const int ys    = strip * STRIP;

    const float* __restrict__ p0 = in + (size_t)b * 3 * HW;
    const float* __restrict__ p1 = p0 + HW;
    const float* __restrict__ p2 = p1 + HW;

    // reflected column indices (computed once; borders handled here)
    int colo[7];
    #pragma unroll
    for (int c = 0; c < 7; ++c) colo[c] = reflect512(x - 3 + c);

    // rolling window: slot (k+j)%7 holds image row ys+k-3+j at step k
    float w0[7][7], w1[7][7], w2[7][7];
    #pragma unroll
    for (int j = 0; j < 7; ++j) {
        int rb = reflect512(ys - 3 + j) * WW;
        #pragma unroll
        for (int c = 0; c < 7; ++c) {
            int o = rb + colo[c];
            w0[j][c] = p0[o]; w1[j][c] = p1[o]; w2[j][c] = p2[o];
        }
    }

    // log2 of unnormalized 1-D spatial gaussian (normalization cancels in num/den)
    const float ls7[7] = {-0.01472138f, -0.00654284f, -0.00163571f, 0.f,
                          -0.00163571f, -0.00654284f, -0.01472138f};
    const float K2 = -0.00721347520445f;   // (-0.5/10^2) * log2(e)

    #pragma unroll
    for (int k = 0; k < STRIP; ++k) {
        // prefetch next window row into temps (becomes slot k%7 at step k+1);
        // issued before the ~1100-cycle tap block so latency is hidden by ILP
        float t0[7], t1[7], t2[7];
        if (k < STRIP - 1) {
            int rb = reflect512(ys + k + 4) * WW;
            #pragma unroll
            for (int c = 0; c < 7; ++c) {
                int o = rb + colo[c];
                t0[c] = p0[o]; t1[c] = p1[o]; t2[c] = p2[o];
            }
        }

        const int cs = (k + 3) % 7;        // compile-time
        const float c0 = w0[cs][3], c1 = w1[cs][3], c2 = w2[cs][3];
        float n0 = 0.f, n1 = 0.f, n2 = 0.f, dn = 0.f;

        #pragma unroll
        for (int j = 0; j < 7; ++j) {
            const int s = (k + j) % 7;     // compile-time
            #pragma unroll
            for (int c = 0; c < 7; ++c) {
                float a0 = w0[s][c], a1 = w1[s][c], a2 = w2[s][c];
                float d  = fabsf(a0 - c0) + fabsf(a1 - c1) + fabsf(a2 - c2);
                float wt = __builtin_amdgcn_exp2f(fmaf(K2, d * d, ls7[j] + ls7[c]));
                n0 += wt * a0; n1 += wt * a1; n2 += wt * a2; dn += wt;
            }
        }

        const float inv = 1.0f / dn;
        size_t ob = (size_t)b * 3 * HW + (size_t)(ys + k) * WW + x;
        out[ob]          = n0 * inv;
        out[ob + HW]     = n1 * inv;
        out[ob + 2 * HW] = n2 * inv;

        if (k < STRIP - 1) {               // rotate: new row -> slot k%7 (dead top row)
            const int ns = k % 7;
            #pragma unroll
            for (int c = 0; c < 7; ++c) {
                w0[ns][c] = t0[c]; w1[ns][c] = t1[c]; w2[ns][c] = t2[c];
            }
        }
    }
}

extern "C" void kernel_launch(void* const* d_in, const int* in_sizes, int n_in,
                              void* d_out, int out_size, void* d_ws, size_t ws_size,
                              hipStream_t stream) {
    const float* in = (const float*)d_in[0];
    float* out = (float*)d_out;
    int blocks = BB * (WW / 256) * (HH / STRIP);   // 8 * 2 * 32 = 512
    bilateral_march<<<blocks, 256, 0, stream>>>(in, out);
}